// Round 8
// baseline (518.778 us; speedup 1.0000x reference)
//
#include <hip/hip_runtime.h>

// Problem constants
#define S_DIM 8192
#define K_DIM 1024
#define RO_DIM 4096
#define O_DIM 64
#define SO (S_DIM * O_DIM)

typedef __attribute__((ext_vector_type(8))) __bf16 bf16x8;
typedef __attribute__((ext_vector_type(4))) float floatx4;
typedef __attribute__((ext_vector_type(4))) unsigned short ushx4;

__device__ inline unsigned short f2bf(float f) {
  unsigned u = __builtin_bit_cast(unsigned, f);
  u += 0x7fff + ((u >> 16) & 1);  // round-to-nearest-even
  return (unsigned short)(u >> 16);
}
__device__ inline float bf2f(unsigned short h) {
  unsigned u = ((unsigned)h) << 16;
  return __builtin_bit_cast(float, u);
}

// ---------------------------------------------------------------- cast X,W -> bf16 (+ zero tickets)
__global__ __launch_bounds__(256) void cast_kernel(const float* __restrict__ X,
                                                   const float* __restrict__ W,
                                                   unsigned short* __restrict__ Xb,
                                                   unsigned short* __restrict__ Wb,
                                                   int* __restrict__ tickets) {
  if (blockIdx.x == 0 && threadIdx.x < 64) tickets[threadIdx.x] = 0;  // d_ws is 0xAA-poisoned
  const int NX4 = (S_DIM * K_DIM) / 4;  // multiple of 1024 -> block-uniform branch
#pragma unroll
  for (int i = 0; i < 4; ++i) {
    int g = blockIdx.x * 1024 + i * 256 + threadIdx.x;
    float4 v;
    unsigned short* dst;
    if (g < NX4) {
      v = ((const float4*)X)[g];
      dst = Xb + (size_t)g * 4;
    } else {
      int j = g - NX4;
      v = ((const float4*)W)[j];
      dst = Wb + (size_t)j * 4;
    }
    ushx4 o;
    o.x = f2bf(v.x); o.y = f2bf(v.y); o.z = f2bf(v.z); o.w = f2bf(v.w);
    *(ushx4*)dst = o;
  }
}

// ---------------------------------------------------------------- fused GEMM+sigmoid+rule-reduce
// R6 structure (best so far: gemm 105.6us, 0 conflicts):
// 128x128 tile, BK=64 (16 k0-iters), 4 waves x 16x16x32 MFMA. Wave (wm,oh) =
// rows wm*64..+63 x cols {oh*32..+31} of BOTH rule halves; rule-sum
// lam0*sig(h0)+lam1*sig(h1) entirely in registers.
// - K-chunk XOR swizzle (row&7) at the GLOBAL address of global_load_lds
//   (LDS dest stays wave-uniform + lane*16); read applies the same XOR.
// - Bias folded into acc init (exact); lambda via 1KB LDS side-buffer.
// - NO min-waves bound (R2: forced occupancy spilled acc -> 417MB scratch).
// - NO rule-loop (R7: re-running the K-loop per rule-pair cost +194MB fetch).
// - NEW (R8): final cross-N reduce folded into the gemm tail via the
//   threadfence-ticket pattern; the 32nd block per s-tile sums the 32
//   LLC-hot slices and writes Y. Removes the reduce launch + its HBM re-read.
__global__ __launch_bounds__(256) void gemm_kernel(const unsigned short* __restrict__ Xb,
                                                   const unsigned short* __restrict__ Wb,
                                                   const float* __restrict__ bias,
                                                   const float* __restrict__ lam,
                                                   unsigned short* __restrict__ partial,
                                                   int* __restrict__ tickets,
                                                   float* __restrict__ Y) {
  __shared__ __align__(16) unsigned char smem[33792];
  unsigned short* Atile = (unsigned short*)smem;           // 128 rows x 64 k (16 KB)
  unsigned short* Btile = (unsigned short*)(smem + 16384); // 16 KB
  float* lamsh = (float*)(smem + 32768);                   // [128][2] (1 KB)
  __shared__ int isLast;

  const int t = threadIdx.x;
  const int lane = t & 63;
  const int w = t >> 6;
  const int wm = w & 1;        // wave row half (rows wm*64..+63)
  const int oh = w >> 1;       // o-column half (cols oh*32..+31 of each rule)
  const int quad = lane >> 4;  // 0..3
  const int l16 = lane & 15;
  const int gm0 = blockIdx.y * 128;
  const int gn0 = blockIdx.x * 128;

  // stage lambda interleaved: lamsh[row*2+rl] = lam[gm0+row, bx*2+rl]
  {
    int row = t >> 1, rl = t & 1;
    lamsh[t] = lam[(size_t)(gm0 + row) * 64 + blockIdx.x * 2 + rl];
  }

  // acc init = bias (C/D col = l16, same for all 4 regs) — exact fold
  floatx4 acc[4][2][2];
#pragma unroll
  for (int rh = 0; rh < 2; ++rh)
#pragma unroll
    for (int ni = 0; ni < 2; ++ni) {
      float bv = bias[gn0 + rh * 64 + oh * 32 + ni * 16 + l16];
#pragma unroll
      for (int mi = 0; mi < 4; ++mi)
        acc[mi][rh][ni] = (floatx4){bv, bv, bv, bv};
    }

  for (int k0 = 0; k0 < K_DIM; k0 += 64) {
    __syncthreads();
#pragma unroll
    for (int i = 0; i < 4; ++i) {
      int idx = i * 256 + t;       // 0..1023, lane-contiguous within each wave
      int row = idx >> 3;          // tile row 0..127
      int cc = idx & 7;            // LDS chunk slot within BK=64 (8 x 8 elems)
      int gcc = cc ^ (row & 7);    // global k-chunk held in this slot
      const unsigned short* ga = Xb + (size_t)(gm0 + row) * K_DIM + k0 + gcc * 8;
      const unsigned short* gb = Wb + (size_t)(gn0 + row) * K_DIM + k0 + gcc * 8;
      __builtin_amdgcn_global_load_lds(
          (const __attribute__((address_space(1))) void*)ga,
          (__attribute__((address_space(3))) void*)(Atile + idx * 8), 16, 0, 0);
      __builtin_amdgcn_global_load_lds(
          (const __attribute__((address_space(1))) void*)gb,
          (__attribute__((address_space(3))) void*)(Btile + idx * 8), 16, 0, 0);
    }
    __syncthreads();

    // two k-steps of 32; lane needs k = s*32 + quad*8 -> slot = (s*4+quad)^(row&7)
#pragma unroll
    for (int s = 0; s < 2; ++s) {
      bf16x8 af[4], bfr[2][2];
#pragma unroll
      for (int mi = 0; mi < 4; ++mi) {
        int row = wm * 64 + mi * 16 + l16;
        int cc = (s * 4 + quad) ^ (row & 7);
        af[mi] = *(const bf16x8*)(Atile + row * 64 + cc * 8);
      }
#pragma unroll
      for (int rh = 0; rh < 2; ++rh)
#pragma unroll
        for (int ni = 0; ni < 2; ++ni) {
          int row = rh * 64 + oh * 32 + ni * 16 + l16;
          int cc = (s * 4 + quad) ^ (row & 7);
          bfr[rh][ni] = *(const bf16x8*)(Btile + row * 64 + cc * 8);
        }
#pragma unroll
      for (int mi = 0; mi < 4; ++mi)
#pragma unroll
        for (int rh = 0; rh < 2; ++rh)
#pragma unroll
          for (int ni = 0; ni < 2; ++ni)
            acc[mi][rh][ni] =
                __builtin_amdgcn_mfma_f32_16x16x32_bf16(af[mi], bfr[rh][ni], acc[mi][rh][ni], 0, 0, 0);
    }
  }

  // ---- epilogue: pure-register rule-sum, direct bf16 slice store ----
  unsigned short* pbase = partial + (size_t)blockIdx.x * SO + (size_t)gm0 * O_DIM;
#pragma unroll
  for (int mi = 0; mi < 4; ++mi) {
#pragma unroll
    for (int reg = 0; reg < 4; ++reg) {
      int row = wm * 64 + mi * 16 + quad * 4 + reg;
      float2 lv = *(const float2*)(lamsh + row * 2);
#pragma unroll
      for (int ni = 0; ni < 2; ++ni) {
        float h0 = 1.f / (1.f + __expf(-acc[mi][0][ni][reg]));
        float h1 = 1.f / (1.f + __expf(-acc[mi][1][ni][reg]));
        float y = lv.x * h0 + lv.y * h1;
        pbase[(size_t)row * O_DIM + oh * 32 + ni * 16 + l16] = f2bf(y);
      }
    }
  }

  // ---- ticket: last block per s-tile reduces the 32 slices (LLC-hot) ----
  __threadfence();     // make this block's slice device-visible
  __syncthreads();     // all threads fenced before the ticket bump
  if (t == 0) isLast = (atomicAdd(&tickets[blockIdx.y], 1) == 31) ? 1 : 0;
  __syncthreads();
  if (isLast) {
    __threadfence();   // acquire: see all 32 slices
    const unsigned short* rbase = partial + (size_t)gm0 * O_DIM;
    float* ybase = Y + (size_t)gm0 * O_DIM;
#pragma unroll
    for (int j = 0; j < 8; ++j) {
      int g = j * 256 + t;  // ushx4 group within the 8192-elem s-tile, 2048 total
      float s0 = 0.f, s1 = 0.f, s2 = 0.f, s3 = 0.f;
      for (int c = 0; c < 32; ++c) {
        ushx4 v = *(const ushx4*)(rbase + (size_t)c * SO + g * 4);
        s0 += bf2f(v.x); s1 += bf2f(v.y); s2 += bf2f(v.z); s3 += bf2f(v.w);
      }
      ((float4*)ybase)[g] = (float4){s0, s1, s2, s3};
    }
  }
}

extern "C" void kernel_launch(void* const* d_in, const int* in_sizes, int n_in,
                              void* d_out, int out_size, void* d_ws, size_t ws_size,
                              hipStream_t stream) {
  const float* X = (const float*)d_in[0];     // [8192,1024]
  const float* W = (const float*)d_in[1];     // [4096,1024]
  const float* b = (const float*)d_in[2];     // [4096]
  const float* lam = (const float*)d_in[3];   // [8192,64]
  float* Y = (float*)d_out;                   // [8192,64]

  unsigned short* Xb = (unsigned short*)d_ws;                       // 16 MB
  unsigned short* Wb = Xb + (size_t)S_DIM * K_DIM;                  // 8 MB
  unsigned short* partial = Wb + (size_t)RO_DIM * K_DIM;            // 32 slices x 1 MB = 32 MB
  int* tickets = (int*)(partial + (size_t)32 * SO);                 // 64 ints

  int nCast = ((S_DIM + RO_DIM) * K_DIM / 4) / 1024;  // 3072 blocks
  cast_kernel<<<nCast, 256, 0, stream>>>(X, W, Xb, Wb, tickets);

  dim3 g(RO_DIM / 128, S_DIM / 128);  // (32, 64)
  gemm_kernel<<<g, 256, 0, stream>>>(Xb, Wb, b, lam, partial, tickets, Y);
}

// Round 9
// 187.927 us; speedup vs baseline: 2.7605x; 2.7605x over previous
//
#include <hip/hip_runtime.h>

// Problem constants
#define S_DIM 8192
#define K_DIM 1024
#define RO_DIM 4096
#define O_DIM 64
#define SO (S_DIM * O_DIM)

typedef __attribute__((ext_vector_type(8))) __bf16 bf16x8;
typedef __attribute__((ext_vector_type(4))) float floatx4;
typedef __attribute__((ext_vector_type(4))) unsigned short ushx4;
typedef __attribute__((ext_vector_type(8))) unsigned short ushx8;

__device__ inline unsigned short f2bf(float f) {
  unsigned u = __builtin_bit_cast(unsigned, f);
  u += 0x7fff + ((u >> 16) & 1);  // round-to-nearest-even
  return (unsigned short)(u >> 16);
}
__device__ inline float bf2f(unsigned short h) {
  unsigned u = ((unsigned)h) << 16;
  return __builtin_bit_cast(float, u);
}

// ---------------------------------------------------------------- cast
// X -> Xb row-major bf16 (for global_load_lds A staging).
// W -> Wt fragment-major bf16: chunk c = n16*2048 + kc*16 + nl holds
// W[n16*16+nl][kc*8 .. kc*8+7]. A wave's B-fragment load (16 rows x 8 k) is
// then 1 KB CONTIGUOUS -> one coalesced global_load_dwordx4 per lane.
__global__ __launch_bounds__(256) void cast_kernel(const float* __restrict__ X,
                                                   const float* __restrict__ W,
                                                   unsigned short* __restrict__ Xb,
                                                   unsigned short* __restrict__ Wt) {
  int b = blockIdx.x;
  if (b < 2048) {  // X: 2,097,152 float4 groups, 4 per thread
#pragma unroll
    for (int i = 0; i < 4; ++i) {
      int g = b * 1024 + i * 256 + threadIdx.x;
      float4 v = ((const float4*)X)[g];
      ushx4 o;
      o.x = f2bf(v.x); o.y = f2bf(v.y); o.z = f2bf(v.z); o.w = f2bf(v.w);
      *(ushx4*)(Xb + (size_t)g * 4) = o;
    }
  } else {  // W: 524,288 8-elem chunks, 4 per thread; coalesced writes
    int wb = b - 2048;  // 0..511
#pragma unroll
    for (int i = 0; i < 4; ++i) {
      int c = wb * 1024 + i * 256 + threadIdx.x;
      int n16 = c >> 11;
      int r = c & 2047;
      int kc = r >> 4;
      int nl = r & 15;
      const float* src = W + (size_t)(n16 * 16 + nl) * K_DIM + kc * 8;
      float4 v0 = *(const float4*)src;
      float4 v1 = *(const float4*)(src + 4);
      ushx8 o;
      o[0] = f2bf(v0.x); o[1] = f2bf(v0.y); o[2] = f2bf(v0.z); o[3] = f2bf(v0.w);
      o[4] = f2bf(v1.x); o[5] = f2bf(v1.y); o[6] = f2bf(v1.z); o[7] = f2bf(v1.w);
      *(ushx8*)(Wt + (size_t)c * 8) = o;
    }
  }
}

// ---------------------------------------------------------------- fused GEMM+sigmoid+rule-reduce
// R6 frame (128x128 tile, BK=64, 4 waves x 16x16x32, zero conflicts) with the
// LDS-bandwidth fix: B STREAMED FROM GLOBAL (Wt fragment layout) instead of
// LDS. Model: R6 moved 96 KB/iter through the LDS pipe (~1130 cyc/iter/CU =
// ~60us/CU over 8 blocks) -> LDS-BW-bound. Now only A is staged: 48 KB/iter.
// W (8 MB) is L2/LLC-resident; B-frag loads are 1 KB contiguous per wave.
// - K-chunk XOR swizzle (row&7) at the GLOBAL address of global_load_lds.
// - Bias folded into acc init (exact); lambda via 1KB LDS side-buffer.
// - NO min-waves bound (R2: forced occupancy -> acc spill -> 417MB scratch).
// - NO rule-loop (R7: +194MB fetch). NO threadfence ticket (R8: device-scope
//   fence per block serializes non-coherent XCD L2s -> 518us).
// - fp8/MX rejected on numerics (threshold 0.46, bf16 absmax already 0.125).
__global__ __launch_bounds__(256) void gemm_kernel(const unsigned short* __restrict__ Xb,
                                                   const unsigned short* __restrict__ Wt,
                                                   const float* __restrict__ bias,
                                                   const float* __restrict__ lam,
                                                   unsigned short* __restrict__ partial) {
  __shared__ __align__(16) unsigned char smem[17408];
  unsigned short* Atile = (unsigned short*)smem;           // 128 rows x 64 k (16 KB)
  float* lamsh = (float*)(smem + 16384);                   // [128][2] (1 KB)

  const int t = threadIdx.x;
  const int lane = t & 63;
  const int w = t >> 6;
  const int wm = w & 1;        // wave row half (rows wm*64..+63)
  const int oh = w >> 1;       // o-column half (cols oh*32..+31 of each rule)
  const int quad = lane >> 4;  // 0..3
  const int l16 = lane & 15;
  const int gm0 = blockIdx.y * 128;
  const int gn0 = blockIdx.x * 128;
  const int n16base = blockIdx.x * 8;  // gn0/16

  // stage lambda interleaved: lamsh[row*2+rl] = lam[gm0+row, bx*2+rl]
  {
    int row = t >> 1, rl = t & 1;
    lamsh[t] = lam[(size_t)(gm0 + row) * 64 + blockIdx.x * 2 + rl];
  }

  // acc init = bias (C/D col = l16, same for all 4 regs) — exact fold
  floatx4 acc[4][2][2];
#pragma unroll
  for (int rh = 0; rh < 2; ++rh)
#pragma unroll
    for (int ni = 0; ni < 2; ++ni) {
      float bv = bias[gn0 + rh * 64 + oh * 32 + ni * 16 + l16];
#pragma unroll
      for (int mi = 0; mi < 4; ++mi)
        acc[mi][rh][ni] = (floatx4){bv, bv, bv, bv};
    }

  for (int k0 = 0; k0 < K_DIM; k0 += 64) {
    __syncthreads();
    // A staging: 1024 16B chunks by 256 threads (4 global_load_lds each)
#pragma unroll
    for (int i = 0; i < 4; ++i) {
      int idx = i * 256 + t;       // 0..1023
      int row = idx >> 3;          // tile row 0..127
      int cc = idx & 7;            // LDS chunk slot within BK=64
      int gcc = cc ^ (row & 7);    // global k-chunk held in this slot
      const unsigned short* ga = Xb + (size_t)(gm0 + row) * K_DIM + k0 + gcc * 8;
      __builtin_amdgcn_global_load_lds(
          (const __attribute__((address_space(1))) void*)ga,
          (__attribute__((address_space(3))) void*)(Atile + idx * 8), 16, 0, 0);
    }

    // B fragments for both k-steps: 8 coalesced 16B/lane register loads,
    // no LDS dependency (they ride through the barrier in regs)
    bf16x8 bfr[2][2][2];  // [s][rh][ni]
#pragma unroll
    for (int s = 0; s < 2; ++s)
#pragma unroll
      for (int rh = 0; rh < 2; ++rh)
#pragma unroll
        for (int ni = 0; ni < 2; ++ni) {
          int n16 = n16base + rh * 4 + oh * 2 + ni;
          int kc = (k0 >> 3) + s * 4 + quad;
          bfr[s][rh][ni] = *(const bf16x8*)(Wt + (((size_t)n16 * 128 + kc) * 16 + l16) * 8);
        }

    __syncthreads();

#pragma unroll
    for (int s = 0; s < 2; ++s) {
      bf16x8 af[4];
#pragma unroll
      for (int mi = 0; mi < 4; ++mi) {
        int row = wm * 64 + mi * 16 + l16;
        int cc = (s * 4 + quad) ^ (row & 7);
        af[mi] = *(const bf16x8*)(Atile + row * 64 + cc * 8);
      }
#pragma unroll
      for (int mi = 0; mi < 4; ++mi)
#pragma unroll
        for (int rh = 0; rh < 2; ++rh)
#pragma unroll
          for (int ni = 0; ni < 2; ++ni)
            acc[mi][rh][ni] = __builtin_amdgcn_mfma_f32_16x16x32_bf16(
                af[mi], bfr[s][rh][ni], acc[mi][rh][ni], 0, 0, 0);
    }
  }

  // ---- epilogue: pure-register rule-sum, direct bf16 slice store ----
  unsigned short* pbase = partial + (size_t)blockIdx.x * SO + (size_t)gm0 * O_DIM;
#pragma unroll
  for (int mi = 0; mi < 4; ++mi) {
#pragma unroll
    for (int reg = 0; reg < 4; ++reg) {
      int row = wm * 64 + mi * 16 + quad * 4 + reg;
      float2 lv = *(const float2*)(lamsh + row * 2);
#pragma unroll
      for (int ni = 0; ni < 2; ++ni) {
        float h0 = 1.f / (1.f + __expf(-acc[mi][0][ni][reg]));
        float h1 = 1.f / (1.f + __expf(-acc[mi][1][ni][reg]));
        float y = lv.x * h0 + lv.y * h1;
        pbase[(size_t)row * O_DIM + oh * 32 + ni * 16 + l16] = f2bf(y);
      }
    }
  }
}

// ---------------------------------------------------------------- final reduce over 32 N-tiles
__global__ __launch_bounds__(256) void reduce_kernel(const unsigned short* __restrict__ partial,
                                                     float* __restrict__ Y) {
  int i4 = blockIdx.x * 256 + threadIdx.x;  // index of a 4-elem group
  float s0 = 0.f, s1 = 0.f, s2 = 0.f, s3 = 0.f;
#pragma unroll
  for (int c = 0; c < 32; ++c) {
    ushx4 v = ((const ushx4*)(partial + (size_t)c * SO))[i4];
    s0 += bf2f(v.x); s1 += bf2f(v.y); s2 += bf2f(v.z); s3 += bf2f(v.w);
  }
  ((float4*)Y)[i4] = (float4){s0, s1, s2, s3};
}

extern "C" void kernel_launch(void* const* d_in, const int* in_sizes, int n_in,
                              void* d_out, int out_size, void* d_ws, size_t ws_size,
                              hipStream_t stream) {
  const float* X = (const float*)d_in[0];     // [8192,1024]
  const float* W = (const float*)d_in[1];     // [4096,1024]
  const float* b = (const float*)d_in[2];     // [4096]
  const float* lam = (const float*)d_in[3];   // [8192,64]
  float* Y = (float*)d_out;                   // [8192,64]

  unsigned short* Xb = (unsigned short*)d_ws;                       // 16 MB
  unsigned short* Wt = Xb + (size_t)S_DIM * K_DIM;                  // 8 MB (fragment layout)
  unsigned short* partial = Wt + (size_t)RO_DIM * K_DIM;            // 32 slices x 1 MB = 32 MB

  cast_kernel<<<2560, 256, 0, stream>>>(X, W, Xb, Wt);

  dim3 g(RO_DIM / 128, S_DIM / 128);  // (32, 64)
  gemm_kernel<<<g, 256, 0, stream>>>(Xb, Wt, b, lam, partial);

  reduce_kernel<<<SO / 1024, 256, 0, stream>>>(partial, Y);
}